// Round 5
// baseline (1110.612 us; speedup 1.0000x reference)
//
#include <hip/hip_runtime.h>

#define Bn   32
#define QL   32
#define DOCn 2048
#define Sn   64
#define En   300
#define Hn   256

typedef short bf16x8 __attribute__((ext_vector_type(8)));
typedef float f32x4  __attribute__((ext_vector_type(4)));

static __device__ __forceinline__ float b2f(short s){
  unsigned int u = ((unsigned int)(unsigned short)s) << 16;
  float f; __builtin_memcpy(&f, &u, 4); return f;
}
static __device__ __forceinline__ short f2b(float f){
  unsigned int u; __builtin_memcpy(&u, &f, 4);
  u = u + 0x7fffu + ((u >> 16) & 1u);
  return (short)(u >> 16);
}
static __device__ __forceinline__ float sigm(float x){ return 1.0f/(1.0f+__expf(-x)); }
static __device__ __forceinline__ float tanhx(float x){ return 1.0f - 2.0f/(__expf(2.0f*x)+1.0f); }
static __device__ __forceinline__ f32x4 mfma16(bf16x8 a, bf16x8 b, f32x4 c){
  return __builtin_amdgcn_mfma_f32_16x16x32_bf16(a, b, c, 0, 0, 0);
}

// ---------------------------------------------------------------- facts ----
__global__ __launch_bounds__(256) void k_facts(
    const int* __restrict__ docs, const int* __restrict__ slens,
    const float* __restrict__ emb, short* __restrict__ facts)
{
  const int blk = blockIdx.x;
  const int b = blk >> 6, s = blk & 63;
  const int* lens = slens + b*Sn;
  int off = 0;
  for (int j = 0; j < s; ++j) off += lens[j];
  const int len = lens[s];
  const int e0 = threadIdx.x;
  float a0 = 0.f, a1 = 0.f;
  const int* dtok = docs + b*DOCn + off;
  for (int l = 0; l < len; ++l){
    const float* row = emb + (long)dtok[l]*En;
    a0 += row[e0];
    if (e0 + 256 < En) a1 += row[e0+256];
  }
  const float inv = 1.0f / (float)(len > 0 ? len : 1);
  short* frow = facts + ((long)b*Sn + s)*En;
  frow[e0] = f2b(a0*inv);
  if (e0 + 256 < En) frow[e0+256] = f2b(a1*inv);
}

// ------------------------------------------------------------- q_xg GEMM ---
__global__ __launch_bounds__(256) void k_xg_q(
    const int* __restrict__ queries, const float* __restrict__ emb,
    const float* __restrict__ wih, const float* __restrict__ bih,
    short* __restrict__ xg)
{
  __shared__ alignas(16) short Al[64][40];
  const int bm = blockIdx.x, bn = blockIdx.y;
  const int tid = threadIdx.x;
  const int l = tid & 63, w = tid >> 6;
  const int wm = w & 1, wn = w >> 1;
  const int l15 = l & 15, lq = l >> 4;

  bf16x8 bfr[2][10];
#pragma unroll
  for (int nt = 0; nt < 2; ++nt){
    const int g = bn*64 + wn*32 + nt*16 + l15;
    const float* wr = wih + (long)g*En;
#pragma unroll
    for (int kk = 0; kk < 10; ++kk){
      const int k0 = kk*32 + lq*8;
      bf16x8 v;
#pragma unroll
      for (int j = 0; j < 8; ++j){
        const int k = k0 + j;
        v[j] = (k < En) ? f2b(wr[k]) : (short)0;
      }
      bfr[nt][kk] = v;
    }
  }

  f32x4 acc[2][2] = {};
  const int arow = tid & 63;
  const int ak8  = (tid >> 6) * 8;
  const int tok  = queries[bm*64 + arow];
  const float* asrc = emb + (long)tok*En;

  for (int kk = 0; kk < 10; ++kk){
#pragma unroll
    for (int j = 0; j < 8; ++j){
      const int k = kk*32 + ak8 + j;
      Al[arow][ak8+j] = (k < En) ? f2b(asrc[k]) : (short)0;
    }
    __syncthreads();
#pragma unroll
    for (int mt = 0; mt < 2; ++mt){
      bf16x8 a = *(const bf16x8*)&Al[wm*32 + mt*16 + l15][lq*8];
      acc[mt][0] = mfma16(a, bfr[0][kk], acc[mt][0]);
      acc[mt][1] = mfma16(a, bfr[1][kk], acc[mt][1]);
    }
    __syncthreads();
  }

#pragma unroll
  for (int nt = 0; nt < 2; ++nt){
    const int c = bn*64 + wn*32 + nt*16 + l15;
    const float bias = bih[c];
#pragma unroll
    for (int mt = 0; mt < 2; ++mt){
      const int r0 = bm*64 + wm*32 + mt*16 + lq*4;
#pragma unroll
      for (int p = 0; p < 4; ++p)
        xg[(long)(r0+p)*768 + c] = f2b(acc[mt][nt][p] + bias);
    }
  }
}

// ------------------------------------------------------------ fact xg GEMM -
// A = facts (2048 x 300 bf16); one GRU's wih at a time; out 2048x768 bf16.
__global__ __launch_bounds__(256) void k_xg_fb(
    const short* __restrict__ facts,
    const float* __restrict__ wih, const float* __restrict__ bih,
    short* __restrict__ xg)
{
  __shared__ alignas(16) short Al[64][40];
  const int bm = blockIdx.x, bn = blockIdx.y;
  const int tid = threadIdx.x;
  const int l = tid & 63, w = tid >> 6;
  const int wm = w & 1, wn = w >> 1;
  const int l15 = l & 15, lq = l >> 4;

  bf16x8 bfr[2][10];
#pragma unroll
  for (int nt = 0; nt < 2; ++nt){
    const int g = bn*64 + wn*32 + nt*16 + l15;
    const float* wr = wih + (long)g*En;
#pragma unroll
    for (int kk = 0; kk < 10; ++kk){
      const int k0 = kk*32 + lq*8;
      bf16x8 v;
#pragma unroll
      for (int j = 0; j < 8; ++j){
        const int k = k0 + j;
        v[j] = (k < En) ? f2b(wr[k]) : (short)0;
      }
      bfr[nt][kk] = v;
    }
  }

  f32x4 acc[2][2] = {};
  const int arow = tid & 63;
  const int ak8  = (tid >> 6) * 8;
  const short* asrc = facts + (long)(bm*64 + arow)*En;

  for (int kk = 0; kk < 10; ++kk){
#pragma unroll
    for (int j = 0; j < 8; ++j){
      const int k = kk*32 + ak8 + j;
      Al[arow][ak8+j] = (k < En) ? asrc[k] : (short)0;
    }
    __syncthreads();
#pragma unroll
    for (int mt = 0; mt < 2; ++mt){
      bf16x8 a = *(const bf16x8*)&Al[wm*32 + mt*16 + l15][lq*8];
      acc[mt][0] = mfma16(a, bfr[0][kk], acc[mt][0]);
      acc[mt][1] = mfma16(a, bfr[1][kk], acc[mt][1]);
    }
    __syncthreads();
  }

#pragma unroll
  for (int nt = 0; nt < 2; ++nt){
    const int c = bn*64 + wn*32 + nt*16 + l15;
    const float bias = bih[c];
#pragma unroll
    for (int mt = 0; mt < 2; ++mt){
      const int r0 = bm*64 + wm*32 + mt*16 + lq*4;
#pragma unroll
      for (int p = 0; p < 4; ++p)
        xg[(long)(r0+p)*768 + c] = f2b(acc[mt][nt][p] + bias);
    }
  }
}

// ------------------------------------------------------- GRU q+f (pass 1) --
// 4 blocks x 512: blocks 0,1 = q-GRU (batch halves), 2,3 = f-GRU.
// OUTPUT IS FLOAT32: q_rep -> dout[0,8192); f_out -> dout[8192, 532480).
__global__ __launch_bounds__(512) void k_gru_qf(
    const short* __restrict__ q_xg, const short* __restrict__ f_xg,
    const float* __restrict__ q_whh, const float* __restrict__ q_bhh,
    const float* __restrict__ f_whh, const float* __restrict__ f_bhh,
    const int* __restrict__ qlens, float* __restrict__ dout)
{
  __shared__ alignas(16) short hl[16*264];
  const int gru = blockIdx.x >> 1;   // 0=q, 1=f
  const int mh  = blockIdx.x & 1;
  const int tid = threadIdx.x;
  const int l = tid & 63, w = tid >> 6;
  const int l15 = l & 15, lq = l >> 4;

  const float* whh = (gru == 0) ? q_whh : f_whh;
  const float* bhh = (gru == 0) ? q_bhh : f_bhh;

  bf16x8 wf[3][2][8];
  float bias[3][2];
#pragma unroll
  for (int gi = 0; gi < 3; ++gi)
#pragma unroll
    for (int s = 0; s < 2; ++s){
      const int g = gi*256 + w*32 + s*16 + l15;
      const float* wr = whh + (long)g*Hn;
#pragma unroll
      for (int kk = 0; kk < 8; ++kk){
        bf16x8 v;
#pragma unroll
        for (int j = 0; j < 8; ++j) v[j] = f2b(wr[kk*32 + lq*8 + j]);
        wf[gi][s][kk] = v;
      }
      bias[gi][s] = bhh[g];
    }

  for (int i = tid; i < 16*264; i += 512) hl[i] = 0;
  float hreg[2][4] = {};
  int qlen_m[4];
#pragma unroll
  for (int p = 0; p < 4; ++p) qlen_m[p] = qlens[mh*16 + lq*4 + p];

  const int T = (gru == 0) ? QL : Sn;
  __syncthreads();

  for (int t = 0; t < T; ++t){
    f32x4 acc[3][2];
#pragma unroll
    for (int gi = 0; gi < 3; ++gi)
#pragma unroll
      for (int s = 0; s < 2; ++s){
        const float bv = bias[gi][s];
        acc[gi][s] = (f32x4){bv, bv, bv, bv};
      }
#pragma unroll
    for (int kk = 0; kk < 8; ++kk){
      bf16x8 a = *(const bf16x8*)&hl[l15*264 + kk*32 + lq*8];
#pragma unroll
      for (int gi = 0; gi < 3; ++gi)
#pragma unroll
        for (int s = 0; s < 2; ++s)
          acc[gi][s] = mfma16(a, wf[gi][s][kk], acc[gi][s]);
    }
    __syncthreads();

#pragma unroll
    for (int s = 0; s < 2; ++s){
      const int c = w*32 + s*16 + l15;
#pragma unroll
      for (int p = 0; p < 4; ++p){
        const int r = lq*4 + p;
        const int b = mh*16 + r;
        const short* xr = (gru == 0)
            ? q_xg + (long)(b*QL + t)*768
            : f_xg + (long)(b*Sn + t)*768;
        const float ir = b2f(xr[c]), iz = b2f(xr[c+256]), in_ = b2f(xr[c+512]);
        const float rr = sigm(ir + acc[0][s][p]);
        const float zz = sigm(iz + acc[1][s][p]);
        const float nn = tanhx(in_ + rr*acc[2][s][p]);
        const float hn = (1.0f - zz)*nn + zz*hreg[s][p];
        hreg[s][p] = hn;
        hl[r*264 + c] = f2b(hn);
        if (gru == 0){
          if (t == qlen_m[p] - 1) dout[b*Hn + c] = hn;           // q_rep fp32
        } else {
          dout[Bn*Hn + ((long)b*Sn + t)*Hn + c] = hn;            // f_out partial
        }
      }
    }
    __syncthreads();
  }
}

// ---------------------------------------------------------- GRU b (pass 2) -
// 2 blocks x 512 (batch halves); fp32 RMW: f_out += h_b. Writes num_facts.
__global__ __launch_bounds__(512) void k_gru_b(
    const short* __restrict__ b_xg,
    const float* __restrict__ b_whh, const float* __restrict__ b_bhh,
    const int* __restrict__ slens, float* __restrict__ dout)
{
  __shared__ alignas(16) short hl[16*264];
  const int mh  = blockIdx.x;
  const int tid = threadIdx.x;
  const int l = tid & 63, w = tid >> 6;
  const int l15 = l & 15, lq = l >> 4;

  if (blockIdx.x == 0 && tid < Bn){
    const int* ls = slens + tid*Sn;
    int cnt = 0;
    for (int ss = 0; ss < Sn; ++ss) cnt += (ls[ss] > 0) ? 1 : 0;
    dout[Bn*Hn + (long)Bn*Sn*Hn + tid] = (float)cnt;             // num_facts fp32
  }

  bf16x8 wf[3][2][8];
  float bias[3][2];
#pragma unroll
  for (int gi = 0; gi < 3; ++gi)
#pragma unroll
    for (int s = 0; s < 2; ++s){
      const int g = gi*256 + w*32 + s*16 + l15;
      const float* wr = b_whh + (long)g*Hn;
#pragma unroll
      for (int kk = 0; kk < 8; ++kk){
        bf16x8 v;
#pragma unroll
        for (int j = 0; j < 8; ++j) v[j] = f2b(wr[kk*32 + lq*8 + j]);
        wf[gi][s][kk] = v;
      }
      bias[gi][s] = b_bhh[g];
    }

  for (int i = tid; i < 16*264; i += 512) hl[i] = 0;
  float hreg[2][4] = {};
  __syncthreads();

  for (int tt = 0; tt < Sn; ++tt){
    const int t = Sn - 1 - tt;
    f32x4 acc[3][2];
#pragma unroll
    for (int gi = 0; gi < 3; ++gi)
#pragma unroll
      for (int s = 0; s < 2; ++s){
        const float bv = bias[gi][s];
        acc[gi][s] = (f32x4){bv, bv, bv, bv};
      }
#pragma unroll
    for (int kk = 0; kk < 8; ++kk){
      bf16x8 a = *(const bf16x8*)&hl[l15*264 + kk*32 + lq*8];
#pragma unroll
      for (int gi = 0; gi < 3; ++gi)
#pragma unroll
        for (int s = 0; s < 2; ++s)
          acc[gi][s] = mfma16(a, wf[gi][s][kk], acc[gi][s]);
    }
    __syncthreads();

#pragma unroll
    for (int s = 0; s < 2; ++s){
      const int c = w*32 + s*16 + l15;
#pragma unroll
      for (int p = 0; p < 4; ++p){
        const int r = lq*4 + p;
        const int b = mh*16 + r;
        const short* xr = b_xg + (long)(b*Sn + t)*768;
        const float ir = b2f(xr[c]), iz = b2f(xr[c+256]), in_ = b2f(xr[c+512]);
        const float rr = sigm(ir + acc[0][s][p]);
        const float zz = sigm(iz + acc[1][s][p]);
        const float nn = tanhx(in_ + rr*acc[2][s][p]);
        const float hn = (1.0f - zz)*nn + zz*hreg[s][p];
        hreg[s][p] = hn;
        hl[r*264 + c] = f2b(hn);
        const long oi = Bn*Hn + ((long)b*Sn + t)*Hn + c;
        dout[oi] = dout[oi] + hn;                                // f_out = h_f + h_b
      }
    }
    __syncthreads();
  }
}

// -------------------------------------------------------------- launch -----
extern "C" void kernel_launch(void* const* d_in, const int* in_sizes, int n_in,
                              void* d_out, int out_size, void* d_ws, size_t ws_size,
                              hipStream_t stream)
{
  const int*   queries = (const int*)d_in[0];
  const int*   qlens   = (const int*)d_in[1];
  const int*   docs    = (const int*)d_in[2];
  const int*   slens   = (const int*)d_in[3];
  const float* emb     = (const float*)d_in[4];
  const float* q_wih   = (const float*)d_in[5];
  const float* q_whh   = (const float*)d_in[6];
  const float* q_bih   = (const float*)d_in[7];
  const float* q_bhh   = (const float*)d_in[8];
  const float* f_wih   = (const float*)d_in[9];
  const float* f_whh   = (const float*)d_in[10];
  const float* f_bih   = (const float*)d_in[11];
  const float* f_bhh   = (const float*)d_in[12];
  const float* b_wih   = (const float*)d_in[13];
  const float* b_whh   = (const float*)d_in[14];
  const float* b_bih   = (const float*)d_in[15];
  const float* b_bhh   = (const float*)d_in[16];

  // Workspace (5.9 MB), xgbuf reused for f then b:
  char* wsb = (char*)d_ws;
  short* xgbuf = (short*)(wsb);              // 2048*768 bf16 = 3,145,728 B
  short* q_xg  = (short*)(wsb + 3145728);    // 1024*768 bf16 = 1,572,864 B
  short* facts = (short*)(wsb + 4718592);    // 2048*300 bf16 = 1,228,800 B

  float* dout = (float*)d_out;               // FP32 output buffer!

  k_facts<<<dim3(Bn*Sn), 256, 0, stream>>>(docs, slens, emb, facts);
  k_xg_q <<<dim3(16, 12), 256, 0, stream>>>(queries, emb, q_wih, q_bih, q_xg);
  k_xg_fb<<<dim3(32, 12), 256, 0, stream>>>(facts, f_wih, f_bih, xgbuf);
  k_gru_qf<<<dim3(4), 512, 0, stream>>>(q_xg, xgbuf, q_whh, q_bhh, f_whh, f_bhh,
                                        qlens, dout);
  k_xg_fb<<<dim3(32, 12), 256, 0, stream>>>(facts, b_wih, b_bih, xgbuf);
  k_gru_b<<<dim3(2), 512, 0, stream>>>(xgbuf, b_whh, b_bhh, slens, dout);
}

// Round 6
// 748.568 us; speedup vs baseline: 1.4836x; 1.4836x over previous
//
#include <hip/hip_runtime.h>

#define Bn   32
#define QL   32
#define DOCn 2048
#define Sn   64
#define En   300
#define Hn   256

typedef short bf16x8 __attribute__((ext_vector_type(8)));
typedef float f32x4  __attribute__((ext_vector_type(4)));

static __device__ __forceinline__ float b2f(short s){
  unsigned int u = ((unsigned int)(unsigned short)s) << 16;
  float f; __builtin_memcpy(&f, &u, 4); return f;
}
static __device__ __forceinline__ short f2b(float f){
  unsigned int u; __builtin_memcpy(&u, &f, 4);
  u = u + 0x7fffu + ((u >> 16) & 1u);
  return (short)(u >> 16);
}
static __device__ __forceinline__ float sigm(float x){ return 1.0f/(1.0f+__expf(-x)); }
static __device__ __forceinline__ float tanhx(float x){ return 1.0f - 2.0f/(__expf(2.0f*x)+1.0f); }
static __device__ __forceinline__ f32x4 mfma16(bf16x8 a, bf16x8 b, f32x4 c){
  return __builtin_amdgcn_mfma_f32_16x16x32_bf16(a, b, c, 0, 0, 0);
}

// ---------------------------------------------------------------- facts ----
__global__ __launch_bounds__(256) void k_facts(
    const int* __restrict__ docs, const int* __restrict__ slens,
    const float* __restrict__ emb, short* __restrict__ facts)
{
  const int blk = blockIdx.x;
  const int b = blk >> 6, s = blk & 63;
  const int* lens = slens + b*Sn;
  int off = 0;
  for (int j = 0; j < s; ++j) off += lens[j];
  const int len = lens[s];
  const int e0 = threadIdx.x;
  float a0 = 0.f, a1 = 0.f;
  const int* dtok = docs + b*DOCn + off;
  for (int l = 0; l < len; ++l){
    const float* row = emb + (long)dtok[l]*En;
    a0 += row[e0];
    if (e0 + 256 < En) a1 += row[e0+256];
  }
  const float inv = 1.0f / (float)(len > 0 ? len : 1);
  short* frow = facts + ((long)b*Sn + s)*En;
  frow[e0] = f2b(a0*inv);
  if (e0 + 256 < En) frow[e0+256] = f2b(a1*inv);
}

// ------------------------------------------------------------- q_xg GEMM ---
__global__ __launch_bounds__(256) void k_xg_q(
    const int* __restrict__ queries, const float* __restrict__ emb,
    const float* __restrict__ wih, const float* __restrict__ bih,
    short* __restrict__ xg)
{
  __shared__ alignas(16) short Al[64][40];
  const int bm = blockIdx.x, bn = blockIdx.y;
  const int tid = threadIdx.x;
  const int l = tid & 63, w = tid >> 6;
  const int wm = w & 1, wn = w >> 1;
  const int l15 = l & 15, lq = l >> 4;

  bf16x8 bfr[2][10];
#pragma unroll
  for (int nt = 0; nt < 2; ++nt){
    const int g = bn*64 + wn*32 + nt*16 + l15;
    const float* wr = wih + (long)g*En;
#pragma unroll
    for (int kk = 0; kk < 10; ++kk){
      const int k0 = kk*32 + lq*8;
      bf16x8 v;
#pragma unroll
      for (int j = 0; j < 8; ++j){
        const int k = k0 + j;
        v[j] = (k < En) ? f2b(wr[k]) : (short)0;
      }
      bfr[nt][kk] = v;
    }
  }

  f32x4 acc[2][2] = {};
  const int arow = tid & 63;
  const int ak8  = (tid >> 6) * 8;
  const int tok  = queries[bm*64 + arow];
  const float* asrc = emb + (long)tok*En;

  for (int kk = 0; kk < 10; ++kk){
#pragma unroll
    for (int j = 0; j < 8; ++j){
      const int k = kk*32 + ak8 + j;
      Al[arow][ak8+j] = (k < En) ? f2b(asrc[k]) : (short)0;
    }
    __syncthreads();
#pragma unroll
    for (int mt = 0; mt < 2; ++mt){
      bf16x8 a = *(const bf16x8*)&Al[wm*32 + mt*16 + l15][lq*8];
      acc[mt][0] = mfma16(a, bfr[0][kk], acc[mt][0]);
      acc[mt][1] = mfma16(a, bfr[1][kk], acc[mt][1]);
    }
    __syncthreads();
  }

#pragma unroll
  for (int nt = 0; nt < 2; ++nt){
    const int c = bn*64 + wn*32 + nt*16 + l15;
    const float bias = bih[c];
#pragma unroll
    for (int mt = 0; mt < 2; ++mt){
      const int r0 = bm*64 + wm*32 + mt*16 + lq*4;
#pragma unroll
      for (int p = 0; p < 4; ++p)
        xg[(long)(r0+p)*768 + c] = f2b(acc[mt][nt][p] + bias);
    }
  }
}

// ------------------------------------------------------------ fact xg GEMM -
// A = facts (2048 x 300 bf16); one GRU's wih at a time; out 2048x768 bf16.
__global__ __launch_bounds__(256) void k_xg_fb(
    const short* __restrict__ facts,
    const float* __restrict__ wih, const float* __restrict__ bih,
    short* __restrict__ xg)
{
  __shared__ alignas(16) short Al[64][40];
  const int bm = blockIdx.x, bn = blockIdx.y;
  const int tid = threadIdx.x;
  const int l = tid & 63, w = tid >> 6;
  const int wm = w & 1, wn = w >> 1;
  const int l15 = l & 15, lq = l >> 4;

  bf16x8 bfr[2][10];
#pragma unroll
  for (int nt = 0; nt < 2; ++nt){
    const int g = bn*64 + wn*32 + nt*16 + l15;
    const float* wr = wih + (long)g*En;
#pragma unroll
    for (int kk = 0; kk < 10; ++kk){
      const int k0 = kk*32 + lq*8;
      bf16x8 v;
#pragma unroll
      for (int j = 0; j < 8; ++j){
        const int k = k0 + j;
        v[j] = (k < En) ? f2b(wr[k]) : (short)0;
      }
      bfr[nt][kk] = v;
    }
  }

  f32x4 acc[2][2] = {};
  const int arow = tid & 63;
  const int ak8  = (tid >> 6) * 8;
  const short* asrc = facts + (long)(bm*64 + arow)*En;

  for (int kk = 0; kk < 10; ++kk){
#pragma unroll
    for (int j = 0; j < 8; ++j){
      const int k = kk*32 + ak8 + j;
      Al[arow][ak8+j] = (k < En) ? asrc[k] : (short)0;
    }
    __syncthreads();
#pragma unroll
    for (int mt = 0; mt < 2; ++mt){
      bf16x8 a = *(const bf16x8*)&Al[wm*32 + mt*16 + l15][lq*8];
      acc[mt][0] = mfma16(a, bfr[0][kk], acc[mt][0]);
      acc[mt][1] = mfma16(a, bfr[1][kk], acc[mt][1]);
    }
    __syncthreads();
  }

#pragma unroll
  for (int nt = 0; nt < 2; ++nt){
    const int c = bn*64 + wn*32 + nt*16 + l15;
    const float bias = bih[c];
#pragma unroll
    for (int mt = 0; mt < 2; ++mt){
      const int r0 = bm*64 + wm*32 + mt*16 + lq*4;
#pragma unroll
      for (int p = 0; p < 4; ++p)
        xg[(long)(r0+p)*768 + c] = f2b(acc[mt][nt][p] + bias);
    }
  }
}

// ------------------------------------------------------------------ GRU ----
// Single pass, 6 blocks x 512: (q,f,b) x 2 batch-halves.
// __launch_bounds__(512,2): 2 waves/SIMD -> 256-VGPR budget so the 192-reg
// weight array stays in registers (round-5 spill: VGPR_Count=128 -> 448us).
__global__ __launch_bounds__(512, 2) void k_gru(
    const short* __restrict__ q_xg, const short* __restrict__ f_xg,
    const short* __restrict__ b_xg,
    const float* __restrict__ q_whh, const float* __restrict__ q_bhh,
    const float* __restrict__ f_whh, const float* __restrict__ f_bhh,
    const float* __restrict__ b_whh, const float* __restrict__ b_bhh,
    const int* __restrict__ qlens,
    short* __restrict__ f_hs, short* __restrict__ b_hs,
    float* __restrict__ dout)
{
  __shared__ alignas(16) short hl[16*264];
  const int gru = blockIdx.x >> 1;   // 0=q, 1=f, 2=b
  const int mh  = blockIdx.x & 1;
  const int tid = threadIdx.x;
  const int l = tid & 63, w = tid >> 6;
  const int l15 = l & 15, lq = l >> 4;

  const float* whh = (gru == 0) ? q_whh : (gru == 1) ? f_whh : b_whh;
  const float* bhh = (gru == 0) ? q_bhh : (gru == 1) ? f_bhh : b_bhh;
  const short* xg  = (gru == 0) ? q_xg  : (gru == 1) ? f_xg  : b_xg;

  bf16x8 wf[3][2][8];
  float bias[3][2];
#pragma unroll
  for (int gi = 0; gi < 3; ++gi)
#pragma unroll
    for (int s = 0; s < 2; ++s){
      const int g = gi*256 + w*32 + s*16 + l15;
      const float* wr = whh + (long)g*Hn;
#pragma unroll
      for (int kk = 0; kk < 8; ++kk){
        bf16x8 v;
#pragma unroll
        for (int j = 0; j < 8; ++j) v[j] = f2b(wr[kk*32 + lq*8 + j]);
        wf[gi][s][kk] = v;
      }
      bias[gi][s] = bhh[g];
    }

  for (int i = tid; i < 16*264; i += 512) hl[i] = 0;
  float hreg[2][4] = {};
  int qlen_m[4];
#pragma unroll
  for (int p = 0; p < 4; ++p) qlen_m[p] = qlens[mh*16 + lq*4 + p];

  const int T = (gru == 0) ? QL : Sn;
  __syncthreads();

  for (int tt = 0; tt < T; ++tt){
    const int t = (gru == 2) ? (T - 1 - tt) : tt;

    f32x4 acc[3][2];
#pragma unroll
    for (int gi = 0; gi < 3; ++gi)
#pragma unroll
      for (int s = 0; s < 2; ++s){
        const float bv = bias[gi][s];
        acc[gi][s] = (f32x4){bv, bv, bv, bv};
      }
#pragma unroll
    for (int kk = 0; kk < 8; ++kk){
      bf16x8 a = *(const bf16x8*)&hl[l15*264 + kk*32 + lq*8];
#pragma unroll
      for (int gi = 0; gi < 3; ++gi)
#pragma unroll
        for (int s = 0; s < 2; ++s)
          acc[gi][s] = mfma16(a, wf[gi][s][kk], acc[gi][s]);
    }
    __syncthreads();

#pragma unroll
    for (int s = 0; s < 2; ++s){
      const int c = w*32 + s*16 + l15;
#pragma unroll
      for (int p = 0; p < 4; ++p){
        const int r = lq*4 + p;
        const int b = mh*16 + r;
        const short* xr = xg + (long)(b*T + t)*768;
        const float ir = b2f(xr[c]), iz = b2f(xr[c+256]), in_ = b2f(xr[c+512]);
        const float rr = sigm(ir + acc[0][s][p]);
        const float zz = sigm(iz + acc[1][s][p]);
        const float nn = tanhx(in_ + rr*acc[2][s][p]);
        const float hn = (1.0f - zz)*nn + zz*hreg[s][p];
        hreg[s][p] = hn;
        hl[r*264 + c] = f2b(hn);
        if (gru == 0){
          if (t == qlen_m[p] - 1) dout[b*Hn + c] = hn;           // q_rep fp32
        } else if (gru == 1){
          f_hs[((long)b*Sn + t)*Hn + c] = f2b(hn);
        } else {
          b_hs[((long)b*Sn + t)*Hn + c] = f2b(hn);
        }
      }
    }
    __syncthreads();
  }
}

// -------------------------------------------------------------- combine ----
__global__ __launch_bounds__(256) void k_combine(
    const short* __restrict__ f_hs, const short* __restrict__ b_hs,
    const int* __restrict__ slens, float* __restrict__ dout)
{
  const int i = blockIdx.x*blockDim.x + threadIdx.x;
  const int n = Bn*Sn*Hn;   // 524288
  if (i < n) dout[Bn*Hn + i] = b2f(f_hs[i]) + b2f(b_hs[i]);
  if (i < Bn){
    const int* ls = slens + i*Sn;
    int cnt = 0;
    for (int s = 0; s < Sn; ++s) cnt += (ls[s] > 0) ? 1 : 0;
    dout[Bn*Hn + (long)n + i] = (float)cnt;
  }
}

// -------------------------------------------------------------- launch -----
extern "C" void kernel_launch(void* const* d_in, const int* in_sizes, int n_in,
                              void* d_out, int out_size, void* d_ws, size_t ws_size,
                              hipStream_t stream)
{
  const int*   queries = (const int*)d_in[0];
  const int*   qlens   = (const int*)d_in[1];
  const int*   docs    = (const int*)d_in[2];
  const int*   slens   = (const int*)d_in[3];
  const float* emb     = (const float*)d_in[4];
  const float* q_wih   = (const float*)d_in[5];
  const float* q_whh   = (const float*)d_in[6];
  const float* q_bih   = (const float*)d_in[7];
  const float* q_bhh   = (const float*)d_in[8];
  const float* f_wih   = (const float*)d_in[9];
  const float* f_whh   = (const float*)d_in[10];
  const float* f_bih   = (const float*)d_in[11];
  const float* f_bhh   = (const float*)d_in[12];
  const float* b_wih   = (const float*)d_in[13];
  const float* b_whh   = (const float*)d_in[14];
  const float* b_bih   = (const float*)d_in[15];
  const float* b_bhh   = (const float*)d_in[16];

  // Workspace (11.2 MB):
  char* wsb = (char*)d_ws;
  short* f_xg  = (short*)(wsb);               // 2048*768 bf16 = 3,145,728 B
  short* b_xg  = (short*)(wsb +  3145728);    // 3,145,728 B
  short* q_xg  = (short*)(wsb +  6291456);    // 1024*768 bf16 = 1,572,864 B
  short* facts = (short*)(wsb +  7864320);    // 2048*300 bf16 = 1,228,800 B
  short* f_hs  = (short*)(wsb +  9093120);    // 32*64*256 bf16 = 1,048,576 B
  short* b_hs  = (short*)(wsb + 10141696);    // 1,048,576 B (end 11,190,272)

  float* dout = (float*)d_out;                // fp32 output buffer

  k_facts<<<dim3(Bn*Sn), 256, 0, stream>>>(docs, slens, emb, facts);
  k_xg_q <<<dim3(16, 12), 256, 0, stream>>>(queries, emb, q_wih, q_bih, q_xg);
  k_xg_fb<<<dim3(32, 12), 256, 0, stream>>>(facts, f_wih, f_bih, f_xg);
  k_xg_fb<<<dim3(32, 12), 256, 0, stream>>>(facts, b_wih, b_bih, b_xg);
  k_gru  <<<dim3(6), 512, 0, stream>>>(q_xg, f_xg, b_xg, q_whh, q_bhh,
                                       f_whh, f_bhh, b_whh, b_bhh,
                                       qlens, f_hs, b_hs, dout);
  k_combine<<<dim3(2048), 256, 0, stream>>>(f_hs, b_hs, slens, dout);
}

// Round 7
// 747.683 us; speedup vs baseline: 1.4854x; 1.0012x over previous
//
#include <hip/hip_runtime.h>

#define Bn   32
#define QL   32
#define DOCn 2048
#define Sn   64
#define En   300
#define Hn   256

typedef short bf16x8 __attribute__((ext_vector_type(8)));
typedef float f32x4  __attribute__((ext_vector_type(4)));

static __device__ __forceinline__ float b2f(short s){
  unsigned int u = ((unsigned int)(unsigned short)s) << 16;
  float f; __builtin_memcpy(&f, &u, 4); return f;
}
static __device__ __forceinline__ short f2b(float f){
  unsigned int u; __builtin_memcpy(&u, &f, 4);
  u = u + 0x7fffu + ((u >> 16) & 1u);
  return (short)(u >> 16);
}
static __device__ __forceinline__ float sigm(float x){ return 1.0f/(1.0f+__expf(-x)); }
static __device__ __forceinline__ float tanhx(float x){ return 1.0f - 2.0f/(__expf(2.0f*x)+1.0f); }
static __device__ __forceinline__ f32x4 mfma16(bf16x8 a, bf16x8 b, f32x4 c){
  return __builtin_amdgcn_mfma_f32_16x16x32_bf16(a, b, c, 0, 0, 0);
}

// ---------------------------------------------------------------- facts ----
__global__ __launch_bounds__(256) void k_facts(
    const int* __restrict__ docs, const int* __restrict__ slens,
    const float* __restrict__ emb, short* __restrict__ facts)
{
  const int blk = blockIdx.x;
  const int b = blk >> 6, s = blk & 63;
  const int* lens = slens + b*Sn;
  int off = 0;
  for (int j = 0; j < s; ++j) off += lens[j];
  const int len = lens[s];
  const int e0 = threadIdx.x;
  float a0 = 0.f, a1 = 0.f;
  const int* dtok = docs + b*DOCn + off;
  for (int l = 0; l < len; ++l){
    const float* row = emb + (long)dtok[l]*En;
    a0 += row[e0];
    if (e0 + 256 < En) a1 += row[e0+256];
  }
  const float inv = 1.0f / (float)(len > 0 ? len : 1);
  short* frow = facts + ((long)b*Sn + s)*En;
  frow[e0] = f2b(a0*inv);
  if (e0 + 256 < En) frow[e0+256] = f2b(a1*inv);
}

// ------------------------------------------------------------- q_xg GEMM ---
__global__ __launch_bounds__(256) void k_xg_q(
    const int* __restrict__ queries, const float* __restrict__ emb,
    const float* __restrict__ wih, const float* __restrict__ bih,
    short* __restrict__ xg)
{
  __shared__ alignas(16) short Al[64][40];
  const int bm = blockIdx.x, bn = blockIdx.y;
  const int tid = threadIdx.x;
  const int l = tid & 63, w = tid >> 6;
  const int wm = w & 1, wn = w >> 1;
  const int l15 = l & 15, lq = l >> 4;

  bf16x8 bfr[2][10];
#pragma unroll
  for (int nt = 0; nt < 2; ++nt){
    const int g = bn*64 + wn*32 + nt*16 + l15;
    const float* wr = wih + (long)g*En;
#pragma unroll
    for (int kk = 0; kk < 10; ++kk){
      const int k0 = kk*32 + lq*8;
      bf16x8 v;
#pragma unroll
      for (int j = 0; j < 8; ++j){
        const int k = k0 + j;
        v[j] = (k < En) ? f2b(wr[k]) : (short)0;
      }
      bfr[nt][kk] = v;
    }
  }

  f32x4 acc[2][2] = {};
  const int arow = tid & 63;
  const int ak8  = (tid >> 6) * 8;
  const int tok  = queries[bm*64 + arow];
  const float* asrc = emb + (long)tok*En;

  for (int kk = 0; kk < 10; ++kk){
#pragma unroll
    for (int j = 0; j < 8; ++j){
      const int k = kk*32 + ak8 + j;
      Al[arow][ak8+j] = (k < En) ? f2b(asrc[k]) : (short)0;
    }
    __syncthreads();
#pragma unroll
    for (int mt = 0; mt < 2; ++mt){
      bf16x8 a = *(const bf16x8*)&Al[wm*32 + mt*16 + l15][lq*8];
      acc[mt][0] = mfma16(a, bfr[0][kk], acc[mt][0]);
      acc[mt][1] = mfma16(a, bfr[1][kk], acc[mt][1]);
    }
    __syncthreads();
  }

#pragma unroll
  for (int nt = 0; nt < 2; ++nt){
    const int c = bn*64 + wn*32 + nt*16 + l15;
    const float bias = bih[c];
#pragma unroll
    for (int mt = 0; mt < 2; ++mt){
      const int r0 = bm*64 + wm*32 + mt*16 + lq*4;
#pragma unroll
      for (int p = 0; p < 4; ++p)
        xg[(long)(r0+p)*768 + c] = f2b(acc[mt][nt][p] + bias);
    }
  }
}

// ------------------------------------------------------------ fact xg GEMM -
// A = facts (2048 x 300 bf16); one GRU's wih at a time; out 2048x768 bf16.
__global__ __launch_bounds__(256) void k_xg_fb(
    const short* __restrict__ facts,
    const float* __restrict__ wih, const float* __restrict__ bih,
    short* __restrict__ xg)
{
  __shared__ alignas(16) short Al[64][40];
  const int bm = blockIdx.x, bn = blockIdx.y;
  const int tid = threadIdx.x;
  const int l = tid & 63, w = tid >> 6;
  const int wm = w & 1, wn = w >> 1;
  const int l15 = l & 15, lq = l >> 4;

  bf16x8 bfr[2][10];
#pragma unroll
  for (int nt = 0; nt < 2; ++nt){
    const int g = bn*64 + wn*32 + nt*16 + l15;
    const float* wr = wih + (long)g*En;
#pragma unroll
    for (int kk = 0; kk < 10; ++kk){
      const int k0 = kk*32 + lq*8;
      bf16x8 v;
#pragma unroll
      for (int j = 0; j < 8; ++j){
        const int k = k0 + j;
        v[j] = (k < En) ? f2b(wr[k]) : (short)0;
      }
      bfr[nt][kk] = v;
    }
  }

  f32x4 acc[2][2] = {};
  const int arow = tid & 63;
  const int ak8  = (tid >> 6) * 8;
  const short* asrc = facts + (long)(bm*64 + arow)*En;

  for (int kk = 0; kk < 10; ++kk){
#pragma unroll
    for (int j = 0; j < 8; ++j){
      const int k = kk*32 + ak8 + j;
      Al[arow][ak8+j] = (k < En) ? asrc[k] : (short)0;
    }
    __syncthreads();
#pragma unroll
    for (int mt = 0; mt < 2; ++mt){
      bf16x8 a = *(const bf16x8*)&Al[wm*32 + mt*16 + l15][lq*8];
      acc[mt][0] = mfma16(a, bfr[0][kk], acc[mt][0]);
      acc[mt][1] = mfma16(a, bfr[1][kk], acc[mt][1]);
    }
    __syncthreads();
  }

#pragma unroll
  for (int nt = 0; nt < 2; ++nt){
    const int c = bn*64 + wn*32 + nt*16 + l15;
    const float bias = bih[c];
#pragma unroll
    for (int mt = 0; mt < 2; ++mt){
      const int r0 = bm*64 + wm*32 + mt*16 + lq*4;
#pragma unroll
      for (int p = 0; p < 4; ++p)
        xg[(long)(r0+p)*768 + c] = f2b(acc[mt][nt][p] + bias);
    }
  }
}

// ------------------------------------------------------------------ GRU ----
// 6 blocks x 1024 threads (16 waves): (q,f,b) x 2 batch-halves of 16 rows.
// Wave w owns a 16-col slice of EACH gate: weights = 3 gates x 8 kk x bf16x8
// = 96 VGPRs/thread -> fits the 128-VGPR cap the backend forces for
// full-occupancy blocks (rounds 5/6: 512-thr blocks pinned at 128 -> the
// 192-reg weight array spilled to scratch -> 500us).
__global__ __launch_bounds__(1024) void k_gru(
    const short* __restrict__ q_xg, const short* __restrict__ f_xg,
    const short* __restrict__ b_xg,
    const float* __restrict__ q_whh, const float* __restrict__ q_bhh,
    const float* __restrict__ f_whh, const float* __restrict__ f_bhh,
    const float* __restrict__ b_whh, const float* __restrict__ b_bhh,
    const int* __restrict__ qlens,
    short* __restrict__ f_hs, short* __restrict__ b_hs,
    float* __restrict__ dout)
{
  __shared__ alignas(16) short hl[16*264];
  const int gru = blockIdx.x >> 1;   // 0=q, 1=f, 2=b
  const int mh  = blockIdx.x & 1;
  const int tid = threadIdx.x;
  const int l = tid & 63, w = tid >> 6;   // 16 waves
  const int l15 = l & 15, lq = l >> 4;

  const float* whh = (gru == 0) ? q_whh : (gru == 1) ? f_whh : b_whh;
  const float* bhh = (gru == 0) ? q_bhh : (gru == 1) ? f_bhh : b_bhh;
  const short* xg  = (gru == 0) ? q_xg  : (gru == 1) ? f_xg  : b_xg;

  // wave w owns gate-col g = gi*256 + w*16 + l15
  bf16x8 wf[3][8];            // 96 VGPRs
  float bias[3];
#pragma unroll
  for (int gi = 0; gi < 3; ++gi){
    const int g = gi*256 + w*16 + l15;
    const float* wr = whh + (long)g*Hn;
#pragma unroll
    for (int kk = 0; kk < 8; ++kk){
      bf16x8 v;
#pragma unroll
      for (int j = 0; j < 8; ++j) v[j] = f2b(wr[kk*32 + lq*8 + j]);
      wf[gi][kk] = v;
    }
    bias[gi] = bhh[g];
  }

  for (int i = tid; i < 16*264; i += 1024) hl[i] = 0;
  float hreg[4] = {};
  int qlen_m[4];
#pragma unroll
  for (int p = 0; p < 4; ++p) qlen_m[p] = qlens[mh*16 + lq*4 + p];

  const int T = (gru == 0) ? QL : Sn;
  __syncthreads();

  for (int tt = 0; tt < T; ++tt){
    const int t = (gru == 2) ? (T - 1 - tt) : tt;

    f32x4 acc[3];
#pragma unroll
    for (int gi = 0; gi < 3; ++gi){
      const float bv = bias[gi];
      acc[gi] = (f32x4){bv, bv, bv, bv};
    }
#pragma unroll
    for (int kk = 0; kk < 8; ++kk){
      bf16x8 a = *(const bf16x8*)&hl[l15*264 + kk*32 + lq*8];
      acc[0] = mfma16(a, wf[0][kk], acc[0]);
      acc[1] = mfma16(a, wf[1][kk], acc[1]);
      acc[2] = mfma16(a, wf[2][kk], acc[2]);
    }
    __syncthreads();   // all h reads done before overwriting

    const int c = w*16 + l15;
#pragma unroll
    for (int p = 0; p < 4; ++p){
      const int r = lq*4 + p;
      const int b = mh*16 + r;
      const short* xr = xg + (long)(b*T + t)*768;
      const float ir = b2f(xr[c]), iz = b2f(xr[c+256]), in_ = b2f(xr[c+512]);
      const float rr = sigm(ir + acc[0][p]);
      const float zz = sigm(iz + acc[1][p]);
      const float nn = tanhx(in_ + rr*acc[2][p]);
      const float hn = (1.0f - zz)*nn + zz*hreg[p];
      hreg[p] = hn;
      hl[r*264 + c] = f2b(hn);
      if (gru == 0){
        if (t == qlen_m[p] - 1) dout[b*Hn + c] = hn;           // q_rep fp32
      } else if (gru == 1){
        f_hs[((long)b*Sn + t)*Hn + c] = f2b(hn);
      } else {
        b_hs[((long)b*Sn + t)*Hn + c] = f2b(hn);
      }
    }
    __syncthreads();
  }
}

// -------------------------------------------------------------- combine ----
__global__ __launch_bounds__(256) void k_combine(
    const short* __restrict__ f_hs, const short* __restrict__ b_hs,
    const int* __restrict__ slens, float* __restrict__ dout)
{
  const int i = blockIdx.x*blockDim.x + threadIdx.x;
  const int n = Bn*Sn*Hn;   // 524288
  if (i < n) dout[Bn*Hn + i] = b2f(f_hs[i]) + b2f(b_hs[i]);
  if (i < Bn){
    const int* ls = slens + i*Sn;
    int cnt = 0;
    for (int s = 0; s < Sn; ++s) cnt += (ls[s] > 0) ? 1 : 0;
    dout[Bn*Hn + (long)n + i] = (float)cnt;
  }
}

// -------------------------------------------------------------- launch -----
extern "C" void kernel_launch(void* const* d_in, const int* in_sizes, int n_in,
                              void* d_out, int out_size, void* d_ws, size_t ws_size,
                              hipStream_t stream)
{
  const int*   queries = (const int*)d_in[0];
  const int*   qlens   = (const int*)d_in[1];
  const int*   docs    = (const int*)d_in[2];
  const int*   slens   = (const int*)d_in[3];
  const float* emb     = (const float*)d_in[4];
  const float* q_wih   = (const float*)d_in[5];
  const float* q_whh   = (const float*)d_in[6];
  const float* q_bih   = (const float*)d_in[7];
  const float* q_bhh   = (const float*)d_in[8];
  const float* f_wih   = (const float*)d_in[9];
  const float* f_whh   = (const float*)d_in[10];
  const float* f_bih   = (const float*)d_in[11];
  const float* f_bhh   = (const float*)d_in[12];
  const float* b_wih   = (const float*)d_in[13];
  const float* b_whh   = (const float*)d_in[14];
  const float* b_bih   = (const float*)d_in[15];
  const float* b_bhh   = (const float*)d_in[16];

  // Workspace (11.2 MB):
  char* wsb = (char*)d_ws;
  short* f_xg  = (short*)(wsb);               // 2048*768 bf16 = 3,145,728 B
  short* b_xg  = (short*)(wsb +  3145728);    // 3,145,728 B
  short* q_xg  = (short*)(wsb +  6291456);    // 1024*768 bf16 = 1,572,864 B
  short* facts = (short*)(wsb +  7864320);    // 2048*300 bf16 = 1,228,800 B
  short* f_hs  = (short*)(wsb +  9093120);    // 32*64*256 bf16 = 1,048,576 B
  short* b_hs  = (short*)(wsb + 10141696);    // 1,048,576 B (end 11,190,272)

  float* dout = (float*)d_out;                // fp32 output buffer

  k_facts<<<dim3(Bn*Sn), 256, 0, stream>>>(docs, slens, emb, facts);
  k_xg_q <<<dim3(16, 12), 256, 0, stream>>>(queries, emb, q_wih, q_bih, q_xg);
  k_xg_fb<<<dim3(32, 12), 256, 0, stream>>>(facts, f_wih, f_bih, f_xg);
  k_xg_fb<<<dim3(32, 12), 256, 0, stream>>>(facts, b_wih, b_bih, b_xg);
  k_gru  <<<dim3(6), 1024, 0, stream>>>(q_xg, f_xg, b_xg, q_whh, q_bhh,
                                        f_whh, f_bhh, b_whh, b_bhh,
                                        qlens, f_hs, b_hs, dout);
  k_combine<<<dim3(2048), 256, 0, stream>>>(f_hs, b_hs, slens, dout);
}